// Round 1
// baseline (9217.646 us; speedup 1.0000x reference)
//
#include <hip/hip_runtime.h>
#include <hip/hip_bf16.h>

// CharRNN: 2-layer LSTM LM + softmax CE. fp32 baseline, correctness-first.
// dims: V=8000, B=64, T=128, H=512.

#define V_SIZE 8000
#define B_SIZE 64
#define T_SIZE 128
#define H_SIZE 512
#define NROW   (B_SIZE * T_SIZE)   // 8192

// ---------------- zero ----------------
__global__ void zero_k(float* __restrict__ p, int n) {
  int i = blockIdx.x * 256 + threadIdx.x;
  if (i < n) p[i] = 0.f;
}

// ---------------- embedding gather ----------------
// x[r][h] = emb[ids[r]][h], r = b*T + t
__global__ void embed_k(const int* __restrict__ ids, const float* __restrict__ emb,
                        float* __restrict__ x) {
  int i = blockIdx.x * 256 + threadIdx.x;   // over NROW * 128 float4s
  int r = i >> 7;
  int c = i & 127;
  int id = ids[r];
  reinterpret_cast<float4*>(x)[(size_t)r * 128 + c] =
      reinterpret_cast<const float4*>(emb)[(size_t)id * 128 + c];
}

// ---------------- fused LSTM cell (one layer, one timestep) ----------------
// gates = [xin, hin] @ W + b  (W is [2H][4H] row-major, gate order i,j,f,o)
// c = c*sig(f) + sig(i)*tanh(j); h = tanh(c)*sig(o)
// Block: 128 threads = 64 batch x 2 h-indices. Grid: H/2 = 256 blocks.
#define KC 64
#define TILEH 2

__device__ __forceinline__ float sigf(float v) { return 1.f / (1.f + expf(-v)); }

__global__ __launch_bounds__(128) void lstm_cell_k(
    const float* __restrict__ xin, int xstride,   // row b at xin + b*xstride
    const float* __restrict__ hin,                // [B][H] contiguous
    const float* __restrict__ W, const float* __restrict__ bias,
    float* __restrict__ cst,                      // [B][H] in/out
    float* __restrict__ hout,                     // [B][H]
    float* __restrict__ hstore, int hstride)      // optional extra store (or null)
{
  __shared__ float inb[B_SIZE][KC + 1];  // +1 pad: 2-way bank alias only (free)
  __shared__ float wb[KC][TILEH * 4];    // columns: cc = gate*2 + hh (broadcast reads)

  const int tid = threadIdx.x;
  const int b   = tid & 63;
  const int hh  = tid >> 6;              // 0..1
  const int h0  = blockIdx.x * TILEH;

  float ai = 0.f, aj = 0.f, af = 0.f, ao = 0.f;

  for (int k0 = 0; k0 < 2 * H_SIZE; k0 += KC) {
    const float* src; int rs;
    if (k0 < H_SIZE) { src = xin + k0; rs = xstride; }
    else             { src = hin + (k0 - H_SIZE); rs = H_SIZE; }

    __syncthreads();  // previous chunk's compute must finish before restage
    // stage input chunk: 64 rows x 64 k = 1024 float4, 8 per thread
#pragma unroll
    for (int q = 0; q < 8; ++q) {
      int f  = tid + 128 * q;
      int r  = f >> 4, c4 = f & 15;
      float4 v = *reinterpret_cast<const float4*>(src + (size_t)r * rs + c4 * 4);
      inb[r][c4 * 4 + 0] = v.x; inb[r][c4 * 4 + 1] = v.y;
      inb[r][c4 * 4 + 2] = v.z; inb[r][c4 * 4 + 3] = v.w;
    }
    // stage weight chunk: 64 k x 8 cols (2 h x 4 gates)
#pragma unroll
    for (int q = 0; q < 4; ++q) {
      int e = tid + 128 * q;
      int k = e >> 3, cc = e & 7;
      int n = (cc >> 1) * H_SIZE + h0 + (cc & 1);
      wb[k][cc] = W[(size_t)(k0 + k) * (4 * H_SIZE) + n];
    }
    __syncthreads();

#pragma unroll
    for (int kk = 0; kk < KC; ++kk) {
      float v = inb[b][kk];
      ai = fmaf(v, wb[kk][0 + hh], ai);
      aj = fmaf(v, wb[kk][2 + hh], aj);
      af = fmaf(v, wb[kk][4 + hh], af);
      ao = fmaf(v, wb[kk][6 + hh], ao);
    }
  }

  const int h = h0 + hh;
  float gi = ai + bias[h];
  float gj = aj + bias[H_SIZE + h];
  float gf = af + bias[2 * H_SIZE + h];
  float go = ao + bias[3 * H_SIZE + h];

  float cold = cst[b * H_SIZE + h];
  float cn = cold * sigf(gf) + sigf(gi) * tanhf(gj);
  float hn = tanhf(cn) * sigf(go);
  cst[b * H_SIZE + h]  = cn;
  hout[b * H_SIZE + h] = hn;
  if (hstore) hstore[(size_t)b * hstride + h] = hn;
}

// ---------------- fused logits + log-softmax + CE ----------------
// Per block: MROWS rows x full V. Online (max,sumexp) per thread over its
// columns, then wave-shfl + cross-wave logsumexp merge. Never materializes logits.
#define MROWS 16
#define NTILE 8   // ceil(8000 / 1024)

__global__ __launch_bounds__(256) void ce_k(
    const float* __restrict__ hsrc,   // [NROW][H]
    const float* __restrict__ Wv,     // [H][V]
    const float* __restrict__ bv,     // [V]
    const int* __restrict__ labels,   // [NROW]
    float* __restrict__ accum)
{
  __shared__ float hl[MROWS][H_SIZE];          // 32 KB
  __shared__ int   ll[MROWS];
  __shared__ float tgt[MROWS];
  __shared__ float wmax[MROWS][4], wsum[MROWS][4];

  const int tid = threadIdx.x;
  const int r0  = blockIdx.x * MROWS;

  // load 16 h-rows: 2048 float4, 8 per thread
#pragma unroll
  for (int q = 0; q < 8; ++q) {
    int f = tid + 256 * q;
    int m = f >> 7, c4 = f & 127;
    float4 v = reinterpret_cast<const float4*>(hsrc + (size_t)(r0 + m) * H_SIZE)[c4];
    *reinterpret_cast<float4*>(&hl[m][c4 * 4]) = v;
  }
  if (tid < MROWS) { ll[tid] = labels[r0 + tid]; tgt[tid] = 0.f; }
  __syncthreads();

  float mx[MROWS], sm[MROWS];
#pragma unroll
  for (int m = 0; m < MROWS; ++m) { mx[m] = -1e30f; sm[m] = 0.f; }

  for (int tile = 0; tile < NTILE; ++tile) {
    int v0 = tile * 1024 + tid * 4;   // 4 consecutive columns per thread
    if (v0 < V_SIZE) {
      float4 acc[MROWS];
#pragma unroll
      for (int m = 0; m < MROWS; ++m) acc[m] = make_float4(0.f, 0.f, 0.f, 0.f);

#pragma unroll 2
      for (int k = 0; k < H_SIZE; ++k) {
        float4 w4 = *reinterpret_cast<const float4*>(Wv + (size_t)k * V_SIZE + v0);
#pragma unroll
        for (int m = 0; m < MROWS; ++m) {
          float hv = hl[m][k];   // wave-uniform -> LDS broadcast
          acc[m].x = fmaf(hv, w4.x, acc[m].x);
          acc[m].y = fmaf(hv, w4.y, acc[m].y);
          acc[m].z = fmaf(hv, w4.z, acc[m].z);
          acc[m].w = fmaf(hv, w4.w, acc[m].w);
        }
      }

      float4 b4 = *reinterpret_cast<const float4*>(bv + v0);
#pragma unroll
      for (int m = 0; m < MROWS; ++m) {
        float l0 = acc[m].x + b4.x, l1 = acc[m].y + b4.y;
        float l2 = acc[m].z + b4.z, l3 = acc[m].w + b4.w;
        int lb = ll[m] - v0;
        if (lb >= 0 && lb < 4) {
          tgt[m] = (lb == 0) ? l0 : (lb == 1) ? l1 : (lb == 2) ? l2 : l3;
        }
        float tm = fmaxf(fmaxf(l0, l1), fmaxf(l2, l3));
        float nm = fmaxf(mx[m], tm);
        sm[m] = sm[m] * expf(mx[m] - nm)
              + expf(l0 - nm) + expf(l1 - nm) + expf(l2 - nm) + expf(l3 - nm);
        mx[m] = nm;
      }
    }
  }

  // wave-level logsumexp merge (64 lanes)
#pragma unroll
  for (int m = 0; m < MROWS; ++m) {
#pragma unroll
    for (int off = 32; off >= 1; off >>= 1) {
      float om = __shfl_xor(mx[m], off, 64);
      float os = __shfl_xor(sm[m], off, 64);
      float nm = fmaxf(mx[m], om);
      sm[m] = sm[m] * expf(mx[m] - nm) + os * expf(om - nm);
      mx[m] = nm;
    }
  }
  int wid = tid >> 6;
  if ((tid & 63) == 0) {
#pragma unroll
    for (int m = 0; m < MROWS; ++m) { wmax[m][wid] = mx[m]; wsum[m][wid] = sm[m]; }
  }
  __syncthreads();

  if (tid < MROWS) {
    float M = wmax[tid][0], S = wsum[tid][0];
#pragma unroll
    for (int w = 1; w < 4; ++w) {
      float om = wmax[tid][w], os = wsum[tid][w];
      float nm = fmaxf(M, om);
      S = S * expf(M - nm) + os * expf(om - nm);
      M = nm;
    }
    float loss = (M + logf(S)) - tgt[tid];
    atomicAdd(accum, loss);
  }
}

__global__ void finish_k(const float* __restrict__ accum, float* __restrict__ out) {
  out[0] = accum[0] * (1.f / (float)NROW);
}

// ---------------- launcher ----------------
extern "C" void kernel_launch(void* const* d_in, const int* in_sizes, int n_in,
                              void* d_out, int out_size, void* d_ws, size_t ws_size,
                              hipStream_t stream) {
  const int*   ids  = (const int*)  d_in[0];
  const int*   tgts = (const int*)  d_in[1];
  const float* emb  = (const float*)d_in[2];
  const float* W1   = (const float*)d_in[3];
  const float* b1   = (const float*)d_in[4];
  const float* W2   = (const float*)d_in[5];
  const float* b2   = (const float*)d_in[6];
  const float* Wv   = (const float*)d_in[7];
  const float* bv   = (const float*)d_in[8];
  float* out = (float*)d_out;

  // ws layout (floats): x[8192*512] | outs[8192*512] | h1[2*B*H] | h2[2*B*H]
  //                     | c1[B*H] | c2[B*H] | accum[1]   -> ~34.2 MB total
  float* x     = (float*)d_ws;
  float* outs  = x    + (size_t)NROW * H_SIZE;
  float* h1    = outs + (size_t)NROW * H_SIZE;
  float* h2    = h1   + 2 * B_SIZE * H_SIZE;
  float* c1    = h2   + 2 * B_SIZE * H_SIZE;
  float* c2    = c1   + B_SIZE * H_SIZE;
  float* accum = c2   + B_SIZE * H_SIZE;

  const int nz = 2 * (2 * B_SIZE * H_SIZE) + 2 * (B_SIZE * H_SIZE) + 1; // 196609
  zero_k<<<(nz + 255) / 256, 256, 0, stream>>>(h1, nz);
  embed_k<<<NROW * 128 / 256, 256, 0, stream>>>(ids, emb, x);

  for (int t = 0; t < T_SIZE; ++t) {
    const float* h1r = h1 + (t & 1) * (B_SIZE * H_SIZE);
    float*       h1w = h1 + ((t + 1) & 1) * (B_SIZE * H_SIZE);
    const float* h2r = h2 + (t & 1) * (B_SIZE * H_SIZE);
    float*       h2w = h2 + ((t + 1) & 1) * (B_SIZE * H_SIZE);

    // layer 1: input = x_t (row stride T*H), recurrent = h1r
    lstm_cell_k<<<H_SIZE / TILEH, 128, 0, stream>>>(
        x + (size_t)t * H_SIZE, T_SIZE * H_SIZE, h1r, W1, b1, c1, h1w, nullptr, 0);
    // layer 2: input = h1w (contiguous), recurrent = h2r; also store to outs
    lstm_cell_k<<<H_SIZE / TILEH, 128, 0, stream>>>(
        h1w, H_SIZE, h2r, W2, b2, c2, h2w, outs + (size_t)t * H_SIZE, T_SIZE * H_SIZE);
  }

  ce_k<<<NROW / MROWS, 256, 0, stream>>>(outs, Wv, bv, tgts, accum);
  finish_k<<<1, 1, 0, stream>>>(accum, out);
}

// Round 2
// 6019.341 us; speedup vs baseline: 1.5313x; 1.5313x over previous
//
#include <hip/hip_runtime.h>
#include <hip/hip_bf16.h>

// CharRNN: 2-layer LSTM LM + softmax CE on MI355X.
// Structure: big input-projection GEMM -> persistent cooperative recurrence
// (1 launch, weights LDS-resident, 129 grid barriers) -> fused CE.
// dims: V=8000, B=64, T=128, H=512.

#define V_SIZE 8000
#define B_SIZE 64
#define T_SIZE 128
#define H_SIZE 512
#define NROW   (B_SIZE * T_SIZE)     // 8192
#define NG     (4 * H_SIZE)          // 2048 gate columns
#define NBLK   256                   // recurrence grid = #CUs
#define NTH    512                   // recurrence block size
#define HB     (H_SIZE * B_SIZE)     // one h-state buffer (elems)

// ---------- bf16 helpers (raw ushort storage) ----------
__device__ __forceinline__ float bf2f(unsigned short u) {
  union { unsigned int i; float f; } x; x.i = ((unsigned int)u) << 16; return x.f;
}
__device__ __forceinline__ unsigned short f2bf(float f) {
  union { float f; unsigned int i; } x; x.f = f;
  unsigned int r = x.i + 0x7fffu + ((x.i >> 16) & 1u);
  return (unsigned short)(r >> 16);
}
__device__ __forceinline__ float sigf(float v) { return 1.f / (1.f + expf(-v)); }

// ---------------- zero ----------------
__global__ void zero_k(float* __restrict__ p, int n) {
  int i = blockIdx.x * 256 + threadIdx.x;
  if (i < n) p[i] = 0.f;
}

// ---------------- G1 = (emb[ids]) @ W1[0:H,:] + b1, stored bf16 [t][col][b] ----------------
__global__ __launch_bounds__(256) void gemm1_k(
    const int* __restrict__ ids, const float* __restrict__ emb,
    const float* __restrict__ W1, const float* __restrict__ b1,
    unsigned short* __restrict__ G1)
{
  __shared__ float hl[16][H_SIZE];   // 32 KB: 16 x-rows
  __shared__ int idq[16];

  const int tid = threadIdx.x;
  const int r0  = blockIdx.x * 16;   // 16 rows, all within one t (16 | 64)
  const int t   = r0 >> 6;
  const int bb  = r0 & 63;

  if (tid < 16) idq[tid] = ids[(bb + tid) * T_SIZE + t];
  __syncthreads();
#pragma unroll
  for (int q = 0; q < 8; ++q) {
    int f = tid + 256 * q;
    int m = f >> 7, c4 = f & 127;
    float4 v = reinterpret_cast<const float4*>(emb + (size_t)idq[m] * H_SIZE)[c4];
    *reinterpret_cast<float4*>(&hl[m][c4 * 4]) = v;
  }
  __syncthreads();

  for (int tile = 0; tile < 2; ++tile) {
    int v0 = tile * 1024 + tid * 4;
    float4 acc[16];
#pragma unroll
    for (int m = 0; m < 16; ++m) acc[m] = make_float4(0.f, 0.f, 0.f, 0.f);

#pragma unroll 2
    for (int k = 0; k < H_SIZE; ++k) {
      float4 w4 = *reinterpret_cast<const float4*>(W1 + (size_t)k * NG + v0);
#pragma unroll
      for (int m = 0; m < 16; ++m) {
        float hv = hl[m][k];
        acc[m].x = fmaf(hv, w4.x, acc[m].x);
        acc[m].y = fmaf(hv, w4.y, acc[m].y);
        acc[m].z = fmaf(hv, w4.z, acc[m].z);
        acc[m].w = fmaf(hv, w4.w, acc[m].w);
      }
    }
    float4 b4 = *reinterpret_cast<const float4*>(b1 + v0);
    size_t base = (size_t)t * NG * B_SIZE + (size_t)v0 * B_SIZE + bb;
#pragma unroll
    for (int m = 0; m < 16; ++m) {
      G1[base + 0 * B_SIZE + m] = f2bf(acc[m].x + b4.x);
      G1[base + 1 * B_SIZE + m] = f2bf(acc[m].y + b4.y);
      G1[base + 2 * B_SIZE + m] = f2bf(acc[m].z + b4.z);
      G1[base + 3 * B_SIZE + m] = f2bf(acc[m].w + b4.w);
    }
  }
}

// ---------------- persistent 2-layer LSTM recurrence ----------------
// 256 blocks (1/CU), 512 threads. Block owns 2 h-indices (8 gate cols) for BOTH
// layers; weight slices live in LDS for the whole kernel. h state in global as
// bf16 [h][b] (coalesced), double-buffered by parity. Phase p: L1(t=p) and
// L2(t=p-1) back-to-back, then one grid barrier. c-state in registers.

__device__ __forceinline__ void stage_chunk(float* __restrict__ dst,
                                            const unsigned short* __restrict__ src) {
  // copy one [128 k][64 b] chunk, bf16 -> f32
  const int tid = threadIdx.x;
#pragma unroll
  for (int q = 0; q < 4; ++q) {
    int f = tid + NTH * q;           // 2048 x short4
    short4 s = *reinterpret_cast<const short4*>(src + (size_t)f * 4);
    float4 v = make_float4(bf2f((unsigned short)s.x), bf2f((unsigned short)s.y),
                           bf2f((unsigned short)s.z), bf2f((unsigned short)s.w));
    *reinterpret_cast<float4*>(dst + (size_t)f * 4) = v;
  }
}

__device__ __forceinline__ void comp_chunk(float a[4], const float* __restrict__ hstc,
                                           const float* __restrict__ wrow,
                                           int rep, int b0) {
#pragma unroll
  for (int kk = 0; kk < 32; ++kk) {
    int k = rep * 32 + kk;
    float w = wrow[k];
    float4 h4 = *reinterpret_cast<const float4*>(hstc + k * B_SIZE + b0);
    a[0] = fmaf(h4.x, w, a[0]);
    a[1] = fmaf(h4.y, w, a[1]);
    a[2] = fmaf(h4.z, w, a[2]);
    a[3] = fmaf(h4.w, w, a[3]);
  }
}

__global__ __launch_bounds__(NTH) void recur_k(
    const float* __restrict__ W1, const float* __restrict__ W2,
    const float* __restrict__ b2, const unsigned short* __restrict__ G1,
    unsigned short* __restrict__ h1g, unsigned short* __restrict__ h2g,
    unsigned short* __restrict__ outs, int* __restrict__ cnt)
{
  __shared__ float w1s[8][H_SIZE];          // 16 KB  recurrent W1 slice
  __shared__ float w2s[8][2 * H_SIZE];      // 32 KB  full-K W2 slice
  __shared__ float hst[2][128 * B_SIZE];    // 64 KB  staged h chunks (dbuf)
  __shared__ float gbuf[4][8][B_SIZE];      // 8 KB   rep-partial gates

  const int tid = threadIdx.x;
  const int bid = blockIdx.x;
  const int h0  = bid * 2;
  const int bq  = tid & 15, cc = (tid >> 4) & 7, rep = tid >> 7;
  const int b0  = bq * 4;

  // ---- one-time weight preload into LDS ----
  for (int idx = tid; idx < 8 * H_SIZE; idx += NTH) {
    int c = idx >> 9, k = idx & 511;
    int col = (c >> 1) * H_SIZE + h0 + (c & 1);
    w1s[c][k] = W1[(size_t)(H_SIZE + k) * NG + col];
  }
  for (int idx = tid; idx < 8 * 2 * H_SIZE; idx += NTH) {
    int c = idx >> 10, k = idx & 1023;
    int col = (c >> 1) * H_SIZE + h0 + (c & 1);
    w2s[c][k] = W2[(size_t)k * NG + col];
  }

  const int pb = tid & 63, phh = (tid >> 6) & 1;   // pointwise mapping (tid<128)
  float c1 = 0.f, c2 = 0.f;
  float bias2v[4] = {0.f, 0.f, 0.f, 0.f};
  if (tid < 128) {
#pragma unroll
    for (int g = 0; g < 4; ++g) bias2v[g] = b2[g * H_SIZE + h0 + phh];
  }
  __syncthreads();

  int target = NBLK;
  for (int p = 0; p <= T_SIZE; ++p) {
    // ================= L1: t = p =================
    if (p < T_SIZE) {
      const unsigned short* h1prev = h1g + ((p + 1) & 1) * HB;
      float a[4] = {0.f, 0.f, 0.f, 0.f};
      stage_chunk(hst[0], h1prev);
      __syncthreads();
#pragma unroll
      for (int c = 0; c < 4; ++c) {
        if (c < 3) stage_chunk(hst[(c + 1) & 1], h1prev + (size_t)(c + 1) * 128 * B_SIZE);
        comp_chunk(a, hst[c & 1], &w1s[cc][c * 128], rep, b0);
        __syncthreads();
      }
      *reinterpret_cast<float4*>(&gbuf[rep][cc][b0]) =
          make_float4(a[0], a[1], a[2], a[3]);
      __syncthreads();
      if (tid < 128) {
        float gg[4];
#pragma unroll
        for (int g = 0; g < 4; ++g) {
          float s = gbuf[0][g * 2 + phh][pb] + gbuf[1][g * 2 + phh][pb]
                  + gbuf[2][g * 2 + phh][pb] + gbuf[3][g * 2 + phh][pb];
          s += bf2f(G1[(size_t)p * NG * B_SIZE + (size_t)(g * H_SIZE + h0 + phh) * B_SIZE + pb]);
          gg[g] = s;
        }
        float cn = c1 * sigf(gg[2]) + sigf(gg[0]) * tanhf(gg[1]);
        float hn = tanhf(cn) * sigf(gg[3]);
        c1 = cn;
        h1g[(size_t)(p & 1) * HB + (size_t)(h0 + phh) * B_SIZE + pb] = f2bf(hn);
      }
      __syncthreads();
    }
    // ================= L2: t2 = p-1 =================
    if (p >= 1) {
      const int t2 = p - 1;
      const unsigned short* h1cur  = h1g + (t2 & 1) * HB;
      const unsigned short* h2prev = h2g + ((t2 + 1) & 1) * HB;
      float a[4] = {0.f, 0.f, 0.f, 0.f};
      stage_chunk(hst[0], h1cur);
      __syncthreads();
#pragma unroll
      for (int c = 0; c < 8; ++c) {
        if (c < 7) {
          const unsigned short* nsrc = (c + 1 < 4)
              ? h1cur + (size_t)(c + 1) * 128 * B_SIZE
              : h2prev + (size_t)(c + 1 - 4) * 128 * B_SIZE;
          stage_chunk(hst[(c + 1) & 1], nsrc);
        }
        comp_chunk(a, hst[c & 1], &w2s[cc][c * 128], rep, b0);
        __syncthreads();
      }
      *reinterpret_cast<float4*>(&gbuf[rep][cc][b0]) =
          make_float4(a[0], a[1], a[2], a[3]);
      __syncthreads();
      if (tid < 128) {
        float gg[4];
#pragma unroll
        for (int g = 0; g < 4; ++g) {
          float s = gbuf[0][g * 2 + phh][pb] + gbuf[1][g * 2 + phh][pb]
                  + gbuf[2][g * 2 + phh][pb] + gbuf[3][g * 2 + phh][pb];
          gg[g] = s + bias2v[g];
        }
        float cn = c2 * sigf(gg[2]) + sigf(gg[0]) * tanhf(gg[1]);
        float hn = tanhf(cn) * sigf(gg[3]);
        c2 = cn;
        unsigned short hb = f2bf(hn);
        h2g[(size_t)(t2 & 1) * HB + (size_t)(h0 + phh) * B_SIZE + pb] = hb;
        outs[(size_t)t2 * HB + (size_t)(h0 + phh) * B_SIZE + pb] = hb;
      }
    }
    // ================= grid barrier =================
    __syncthreads();
    if (tid == 0) {
      __threadfence();
      atomicAdd(cnt, 1);
      while (__hip_atomic_load(cnt, __ATOMIC_RELAXED, __HIP_MEMORY_SCOPE_AGENT) < target) {
        __builtin_amdgcn_s_sleep(1);
      }
      __threadfence();
    }
    __syncthreads();
    target += NBLK;
  }
}

// ---------------- fused logits + log-softmax + CE ----------------
// Block: one t x 16 b-rows x full V, reading bf16 outs[t][h][b].
#define MROWS 16
#define NTILE 8

__global__ __launch_bounds__(256) void ce_k(
    const unsigned short* __restrict__ outs,  // bf16 [T][H][B]
    const float* __restrict__ Wv,             // [H][V]
    const float* __restrict__ bv,             // [V]
    const int* __restrict__ tgts,             // [B][T]
    float* __restrict__ accum)
{
  __shared__ float hl[MROWS][H_SIZE];          // 32 KB
  __shared__ int   ll[MROWS];
  __shared__ float tgt[MROWS];
  __shared__ float wmax[MROWS][4], wsum[MROWS][4];

  const int tid = threadIdx.x;
  const int t   = blockIdx.x & 127;
  const int b0  = (blockIdx.x >> 7) * 16;

#pragma unroll
  for (int q = 0; q < 8; ++q) {
    int f = tid + 256 * q;            // 2048 x short4 over [k][mq]
    int k = f >> 2, mq = f & 3;
    short4 s = *reinterpret_cast<const short4*>(
        outs + (size_t)t * HB + (size_t)k * B_SIZE + b0 + mq * 4);
    hl[mq * 4 + 0][k] = bf2f((unsigned short)s.x);
    hl[mq * 4 + 1][k] = bf2f((unsigned short)s.y);
    hl[mq * 4 + 2][k] = bf2f((unsigned short)s.z);
    hl[mq * 4 + 3][k] = bf2f((unsigned short)s.w);
  }
  if (tid < MROWS) { ll[tid] = tgts[(b0 + tid) * T_SIZE + t]; tgt[tid] = 0.f; }
  __syncthreads();

  float mx[MROWS], sm[MROWS];
#pragma unroll
  for (int m = 0; m < MROWS; ++m) { mx[m] = -1e30f; sm[m] = 0.f; }

  for (int tile = 0; tile < NTILE; ++tile) {
    int v0 = tile * 1024 + tid * 4;
    if (v0 < V_SIZE) {
      float4 acc[MROWS];
#pragma unroll
      for (int m = 0; m < MROWS; ++m) acc[m] = make_float4(0.f, 0.f, 0.f, 0.f);

#pragma unroll 2
      for (int k = 0; k < H_SIZE; ++k) {
        float4 w4 = *reinterpret_cast<const float4*>(Wv + (size_t)k * V_SIZE + v0);
#pragma unroll
        for (int m = 0; m < MROWS; ++m) {
          float hv = hl[m][k];
          acc[m].x = fmaf(hv, w4.x, acc[m].x);
          acc[m].y = fmaf(hv, w4.y, acc[m].y);
          acc[m].z = fmaf(hv, w4.z, acc[m].z);
          acc[m].w = fmaf(hv, w4.w, acc[m].w);
        }
      }

      float4 b4 = *reinterpret_cast<const float4*>(bv + v0);
#pragma unroll
      for (int m = 0; m < MROWS; ++m) {
        float l0 = acc[m].x + b4.x, l1 = acc[m].y + b4.y;
        float l2 = acc[m].z + b4.z, l3 = acc[m].w + b4.w;
        int lb = ll[m] - v0;
        if (lb >= 0 && lb < 4) {
          tgt[m] = (lb == 0) ? l0 : (lb == 1) ? l1 : (lb == 2) ? l2 : l3;
        }
        float tm = fmaxf(fmaxf(l0, l1), fmaxf(l2, l3));
        float nm = fmaxf(mx[m], tm);
        sm[m] = sm[m] * expf(mx[m] - nm)
              + expf(l0 - nm) + expf(l1 - nm) + expf(l2 - nm) + expf(l3 - nm);
        mx[m] = nm;
      }
    }
  }

#pragma unroll
  for (int m = 0; m < MROWS; ++m) {
#pragma unroll
    for (int off = 32; off >= 1; off >>= 1) {
      float om = __shfl_xor(mx[m], off, 64);
      float os = __shfl_xor(sm[m], off, 64);
      float nm = fmaxf(mx[m], om);
      sm[m] = sm[m] * expf(mx[m] - nm) + os * expf(om - nm);
      mx[m] = nm;
    }
  }
  int wid = tid >> 6;
  if ((tid & 63) == 0) {
#pragma unroll
    for (int m = 0; m < MROWS; ++m) { wmax[m][wid] = mx[m]; wsum[m][wid] = sm[m]; }
  }
  __syncthreads();

  if (tid < MROWS) {
    float M = wmax[tid][0], S = wsum[tid][0];
#pragma unroll
    for (int w = 1; w < 4; ++w) {
      float om = wmax[tid][w], os = wsum[tid][w];
      float nm = fmaxf(M, om);
      S = S * expf(M - nm) + os * expf(om - nm);
      M = nm;
    }
    float loss = (M + logf(S)) - tgt[tid];
    atomicAdd(accum, loss);
  }
}

__global__ void finish_k(const float* __restrict__ accum, float* __restrict__ out) {
  out[0] = accum[0] * (1.f / (float)NROW);
}

// ---------------- launcher ----------------
extern "C" void kernel_launch(void* const* d_in, const int* in_sizes, int n_in,
                              void* d_out, int out_size, void* d_ws, size_t ws_size,
                              hipStream_t stream) {
  const int*   ids  = (const int*)  d_in[0];
  const int*   tgts = (const int*)  d_in[1];
  const float* emb  = (const float*)d_in[2];
  const float* W1   = (const float*)d_in[3];
  const float* b1   = (const float*)d_in[4];
  const float* W2   = (const float*)d_in[5];
  const float* b2   = (const float*)d_in[6];
  const float* Wv   = (const float*)d_in[7];
  const float* bv   = (const float*)d_in[8];
  float* out = (float*)d_out;

  // ws layout (bytes):
  //   G1   bf16 [T][2048][64]  33,554,432
  //   outs bf16 [T][512][64]    8,388,608
  //   h1g  bf16 [2][512][64]      131,072
  //   h2g  bf16 [2][512][64]      131,072
  //   cnt  int (4) | accum f32 (4)          total ~42.2 MB
  char* ws = (char*)d_ws;
  unsigned short* G1    = (unsigned short*)(ws);
  unsigned short* outsb = (unsigned short*)(ws + 33554432);
  unsigned short* h1g   = (unsigned short*)(ws + 41943040);
  unsigned short* h2g   = (unsigned short*)(ws + 42074112);
  int*            cnt   = (int*)           (ws + 42205184);
  float*          accum = (float*)         (ws + 42205188);

  // zero h-state + cnt + accum (262,152 B = 65,538 floats)
  zero_k<<<(65538 + 255) / 256, 256, 0, stream>>>((float*)h1g, 65538);

  gemm1_k<<<512, 256, 0, stream>>>(ids, emb, W1, b1, G1);

  {
    void* args[] = { (void*)&W1, (void*)&W2, (void*)&b2, (void*)&G1,
                     (void*)&h1g, (void*)&h2g, (void*)&outsb, (void*)&cnt };
    hipError_t e = hipLaunchCooperativeKernel((const void*)recur_k,
                                              dim3(NBLK), dim3(NTH),
                                              args, 0, stream);
    if (e != hipSuccess) {
      // fallback: plain launch (grid == #CUs, co-resident in practice)
      recur_k<<<dim3(NBLK), dim3(NTH), 0, stream>>>(W1, W2, b2, G1, h1g, h2g,
                                                    outsb, cnt);
    }
  }

  ce_k<<<512, 256, 0, stream>>>(outsb, Wv, bv, tgts, accum);
  finish_k<<<1, 1, 0, stream>>>(accum, out);
}

// Round 3
// 3365.274 us; speedup vs baseline: 2.7390x; 1.7887x over previous
//
#include <hip/hip_runtime.h>
#include <hip/hip_bf16.h>

// CharRNN: 2-layer LSTM LM + softmax CE on MI355X (gfx950).
// Round 2: MFMA recurrence. 128 persistent blocks (64 L1 + 64 L2), weights
// LDS-resident in B-frag order (bf16), h-state bf16 [b][k] in global,
// A-frags loaded straight from global. 129 grid barriers.
// dims: V=8000, B=64, T=128, H=512.

#define V_SIZE 8000
#define B_SIZE 64
#define T_SIZE 128
#define H_SIZE 512
#define NROW   (B_SIZE * T_SIZE)     // 8192
#define NG     (4 * H_SIZE)          // 2048 gate columns
#define HB     (H_SIZE * B_SIZE)     // one h-state buffer (bf16 elems)
#define RBLK   128                   // recurrence grid
#define RTH    256                   // recurrence block size

typedef __attribute__((ext_vector_type(8))) short bf16x8;
typedef __attribute__((ext_vector_type(4))) float f32x4;

// ---------- bf16 helpers (raw ushort storage) ----------
__device__ __forceinline__ float bf2f(unsigned short u) {
  union { unsigned int i; float f; } x; x.i = ((unsigned int)u) << 16; return x.f;
}
__device__ __forceinline__ unsigned short f2bf(float f) {
  union { float f; unsigned int i; } x; x.f = f;
  unsigned int r = x.i + 0x7fffu + ((x.i >> 16) & 1u);
  return (unsigned short)(r >> 16);
}
__device__ __forceinline__ float sigf(float v) { return 1.f / (1.f + expf(-v)); }

// ---------------- zero ----------------
__global__ void zero_k(float* __restrict__ p, int n) {
  int i = blockIdx.x * 256 + threadIdx.x;
  if (i < n) p[i] = 0.f;
}

// ---------------- G1 = (emb[ids]) @ W1[0:H,:] + b1, stored bf16 [t][b][col] ----------------
__global__ __launch_bounds__(256) void gemm1_k(
    const int* __restrict__ ids, const float* __restrict__ emb,
    const float* __restrict__ W1, const float* __restrict__ b1,
    unsigned short* __restrict__ G1)
{
  __shared__ float hl[16][H_SIZE];   // 32 KB: 16 x-rows
  __shared__ int idq[16];

  const int tid = threadIdx.x;
  const int r0  = blockIdx.x * 16;   // 16 rows, all within one t (16 | 64)
  const int t   = r0 >> 6;
  const int bb  = r0 & 63;

  if (tid < 16) idq[tid] = ids[(bb + tid) * T_SIZE + t];
  __syncthreads();
#pragma unroll
  for (int q = 0; q < 8; ++q) {
    int f = tid + 256 * q;
    int m = f >> 7, c4 = f & 127;
    float4 v = reinterpret_cast<const float4*>(emb + (size_t)idq[m] * H_SIZE)[c4];
    *reinterpret_cast<float4*>(&hl[m][c4 * 4]) = v;
  }
  __syncthreads();

  for (int tile = 0; tile < 2; ++tile) {
    int v0 = tile * 1024 + tid * 4;
    float4 acc[16];
#pragma unroll
    for (int m = 0; m < 16; ++m) acc[m] = make_float4(0.f, 0.f, 0.f, 0.f);

#pragma unroll 2
    for (int k = 0; k < H_SIZE; ++k) {
      float4 w4 = *reinterpret_cast<const float4*>(W1 + (size_t)k * NG + v0);
#pragma unroll
      for (int m = 0; m < 16; ++m) {
        float hv = hl[m][k];
        acc[m].x = fmaf(hv, w4.x, acc[m].x);
        acc[m].y = fmaf(hv, w4.y, acc[m].y);
        acc[m].z = fmaf(hv, w4.z, acc[m].z);
        acc[m].w = fmaf(hv, w4.w, acc[m].w);
      }
    }
    float4 b4 = *reinterpret_cast<const float4*>(b1 + v0);
#pragma unroll
    for (int m = 0; m < 16; ++m) {
      size_t base = ((size_t)t * 64 + bb + m) * NG + v0;
      G1[base + 0] = f2bf(acc[m].x + b4.x);
      G1[base + 1] = f2bf(acc[m].y + b4.y);
      G1[base + 2] = f2bf(acc[m].z + b4.z);
      G1[base + 3] = f2bf(acc[m].w + b4.w);
    }
  }
}

// ---------------- persistent MFMA 2-layer LSTM recurrence ----------------
// Blocks 0..63: layer 1 (t=p), own 8 h-cols = 32 gate cols.  K=512 (h1prev).
// Blocks 64..127: layer 2 (t=p-1).                          K=1024 ([h1;h2]).
// Per wave w: C m-tile rows 16w..16w+15, 2 n-groups of 16 cols.
// B-frag (16x16x32): lane l holds B[(l>>4)*8+e][l&15]; A: A[l&15][(l>>4)*8+e];
// C/D: row=(l>>4)*4+r, col=l&15.
__global__ __launch_bounds__(RTH) void recur_k(
    const float* __restrict__ W1, const float* __restrict__ W2,
    const float* __restrict__ b2, const unsigned short* __restrict__ G1,
    unsigned short* __restrict__ h1g, unsigned short* __restrict__ h2g,
    unsigned short* __restrict__ outs, int* __restrict__ cnt)
{
  __shared__ short wlds[2 * 32 * 64 * 8];   // 64 KB (L1 uses half)
  __shared__ float gbuf[64][32];            // 8 KB

  const int tid  = threadIdx.x;
  const int bid  = blockIdx.x;
  const bool isL2 = (bid >= 64);
  const int h0   = (isL2 ? bid - 64 : bid) * 8;
  const int w    = tid >> 6, l = tid & 63;
  const int NK   = isL2 ? 32 : 16;          // ksteps per phase

  // ---- one-time weight preload, bf16 in B-frag order ----
  // wlds[((ng*NK + ks)*64 + lane)*8 + e] = W[(ks*32 + (lane>>4)*8 + e)][col]
  // col(n=lane&15, ng) = (n&3)*512 + h0 + ng*4 + (n>>2)
  {
    const float* Wsrc = isL2 ? W2 : (W1 + (size_t)H_SIZE * NG);
    for (int idx = tid; idx < 2 * NK * 64; idx += RTH) {
      int lane = idx & 63;
      int ks   = (idx >> 6) % NK;
      int ng   = (idx >> 6) / NK;
      int n    = lane & 15;
      int col  = (n & 3) * H_SIZE + h0 + ng * 4 + (n >> 2);
      int kb   = ks * 32 + (lane >> 4) * 8;
      short* dst = &wlds[((size_t)(ng * NK + ks) * 64 + lane) * 8];
#pragma unroll
      for (int e = 0; e < 8; ++e)
        dst[e] = (short)f2bf(Wsrc[(size_t)(kb + e) * NG + col]);
    }
  }

  // pointwise mapping: thread = b*4 + q handles (b, hcols {q, q+4})
  const int pb = tid >> 2, pq = tid & 3;
  float cst[2] = {0.f, 0.f};
  float bias2[2][4];
  if (isL2) {
#pragma unroll
    for (int hh = 0; hh < 2; ++hh)
#pragma unroll
      for (int g = 0; g < 4; ++g)
        bias2[hh][g] = b2[g * H_SIZE + h0 + pq + hh * 4];
  }
  __syncthreads();

  int target = RBLK;
  for (int p = 0; p <= T_SIZE; ++p) {
    const bool active = isL2 ? (p >= 1) : (p < T_SIZE);
    if (active) {
      const int t = isL2 ? p - 1 : p;
      // A sources (bf16 [b][512]):
      //  L1: h1prev = h1g[(p+1)&1]           (K = 0..511)
      //  L2: h1cur  = h1g[t&1] (=(p+1)&1)    (K = 0..511)
      //      h2prev = h2g[(t+1)&1]           (K = 512..1023)
      const unsigned short* asrc1 = isL2 ? (h1g + (size_t)(t & 1) * HB)
                                         : (h1g + (size_t)((p + 1) & 1) * HB);
      const unsigned short* asrc2 = isL2 ? (h2g + (size_t)((t + 1) & 1) * HB)
                                         : asrc1;
      const int arow = w * 16 + (l & 15);
      const unsigned short* a1 = asrc1 + (size_t)arow * H_SIZE + (l >> 4) * 8;
      const unsigned short* a2 = asrc2 + (size_t)arow * H_SIZE + (l >> 4) * 8;

      f32x4 acc0 = {0.f, 0.f, 0.f, 0.f};
      f32x4 acc1 = {0.f, 0.f, 0.f, 0.f};
      if (!isL2) {
#pragma unroll
        for (int ks = 0; ks < 16; ++ks) {
          bf16x8 av = *reinterpret_cast<const bf16x8*>(a1 + ks * 32);
          bf16x8 bv0 = *reinterpret_cast<const bf16x8*>(&wlds[((size_t)(0 * 16 + ks) * 64 + l) * 8]);
          bf16x8 bv1 = *reinterpret_cast<const bf16x8*>(&wlds[((size_t)(1 * 16 + ks) * 64 + l) * 8]);
          acc0 = __builtin_amdgcn_mfma_f32_16x16x32_bf16(av, bv0, acc0, 0, 0, 0);
          acc1 = __builtin_amdgcn_mfma_f32_16x16x32_bf16(av, bv1, acc1, 0, 0, 0);
        }
      } else {
#pragma unroll
        for (int ks = 0; ks < 32; ++ks) {
          const unsigned short* ap = (ks < 16) ? (a1 + ks * 32) : (a2 + (ks - 16) * 32);
          bf16x8 av = *reinterpret_cast<const bf16x8*>(ap);
          bf16x8 bv0 = *reinterpret_cast<const bf16x8*>(&wlds[((size_t)(0 * 32 + ks) * 64 + l) * 8]);
          bf16x8 bv1 = *reinterpret_cast<const bf16x8*>(&wlds[((size_t)(1 * 32 + ks) * 64 + l) * 8]);
          acc0 = __builtin_amdgcn_mfma_f32_16x16x32_bf16(av, bv0, acc0, 0, 0, 0);
          acc1 = __builtin_amdgcn_mfma_f32_16x16x32_bf16(av, bv1, acc1, 0, 0, 0);
        }
      }

      // C -> gbuf: row = w*16 + (l>>4)*4 + r, col = ng*16 + (l&15)
      {
        const int crow = w * 16 + ((l >> 4) << 2);
        const int ccol = l & 15;
#pragma unroll
        for (int r = 0; r < 4; ++r) {
          gbuf[crow + r][ccol]      = acc0[r];
          gbuf[crow + r][16 + ccol] = acc1[r];
        }
      }
      __syncthreads();

      // pointwise: gates i,j,f,o at n = hl*4 + g (hl local 0..7 -> ng=hl>>2)
#pragma unroll
      for (int hh = 0; hh < 2; ++hh) {
        const int hl = pq + hh * 4;
        const int ng = hl >> 2, jj = hl & 3;
        float g[4];
#pragma unroll
        for (int gg = 0; gg < 4; ++gg) g[gg] = gbuf[pb][ng * 16 + jj * 4 + gg];
        if (!isL2) {
#pragma unroll
          for (int gg = 0; gg < 4; ++gg)
            g[gg] += bf2f(G1[((size_t)t * 64 + pb) * NG + gg * H_SIZE + h0 + hl]);
        } else {
#pragma unroll
          for (int gg = 0; gg < 4; ++gg) g[gg] += bias2[hh][gg];
        }
        float cn = cst[hh] * sigf(g[2]) + sigf(g[0]) * tanhf(g[1]);
        float hn = tanhf(cn) * sigf(g[3]);
        cst[hh] = cn;
        unsigned short hb = f2bf(hn);
        if (!isL2) {
          h1g[(size_t)(p & 1) * HB + (size_t)pb * H_SIZE + h0 + hl] = hb;
        } else {
          h2g[(size_t)(t & 1) * HB + (size_t)pb * H_SIZE + h0 + hl] = hb;
          outs[((size_t)t * 64 + pb) * H_SIZE + h0 + hl] = hb;
        }
      }
    }

    // ---------------- grid barrier ----------------
    __syncthreads();
    if (tid == 0) {
      __threadfence();
      atomicAdd(cnt, 1);
      while (__hip_atomic_load(cnt, __ATOMIC_RELAXED, __HIP_MEMORY_SCOPE_AGENT) < target) {
        __builtin_amdgcn_s_sleep(1);
      }
      __threadfence();
    }
    __syncthreads();
    target += RBLK;
  }
}

// ---------------- fused logits + log-softmax + CE ----------------
// Block: one t x 16 b-rows x full V, reading bf16 outs[t][b][h].
#define MROWS 16
#define NTILE 8

__global__ __launch_bounds__(256) void ce_k(
    const unsigned short* __restrict__ outs,  // bf16 [T][B][H]
    const float* __restrict__ Wv,             // [H][V]
    const float* __restrict__ bv,             // [V]
    const int* __restrict__ tgts,             // [B][T]
    float* __restrict__ accum)
{
  __shared__ float hl[MROWS][H_SIZE];          // 32 KB
  __shared__ int   ll[MROWS];
  __shared__ float tgt[MROWS];
  __shared__ float wmax[MROWS][4], wsum[MROWS][4];

  const int tid = threadIdx.x;
  const int t   = blockIdx.x & 127;
  const int b0  = (blockIdx.x >> 7) * 16;

#pragma unroll
  for (int q = 0; q < 8; ++q) {
    int f = tid + 256 * q;            // 2048 short4: 16 rows x 128/row
    int m = f >> 7, c4 = f & 127;
    short4 s = *reinterpret_cast<const short4*>(
        outs + ((size_t)t * 64 + b0 + m) * H_SIZE + c4 * 4);
    hl[m][c4 * 4 + 0] = bf2f((unsigned short)s.x);
    hl[m][c4 * 4 + 1] = bf2f((unsigned short)s.y);
    hl[m][c4 * 4 + 2] = bf2f((unsigned short)s.z);
    hl[m][c4 * 4 + 3] = bf2f((unsigned short)s.w);
  }
  if (tid < MROWS) { ll[tid] = tgts[(b0 + tid) * T_SIZE + t]; tgt[tid] = 0.f; }
  __syncthreads();

  float mx[MROWS], sm[MROWS];
#pragma unroll
  for (int m = 0; m < MROWS; ++m) { mx[m] = -1e30f; sm[m] = 0.f; }

  for (int tile = 0; tile < NTILE; ++tile) {
    int v0 = tile * 1024 + tid * 4;
    if (v0 < V_SIZE) {
      float4 acc[MROWS];
#pragma unroll
      for (int m = 0; m < MROWS; ++m) acc[m] = make_float4(0.f, 0.f, 0.f, 0.f);

#pragma unroll 2
      for (int k = 0; k < H_SIZE; ++k) {
        float4 w4 = *reinterpret_cast<const float4*>(Wv + (size_t)k * V_SIZE + v0);
#pragma unroll
        for (int m = 0; m < MROWS; ++m) {
          float hv = hl[m][k];
          acc[m].x = fmaf(hv, w4.x, acc[m].x);
          acc[m].y = fmaf(hv, w4.y, acc[m].y);
          acc[m].z = fmaf(hv, w4.z, acc[m].z);
          acc[m].w = fmaf(hv, w4.w, acc[m].w);
        }
      }

      float4 b4 = *reinterpret_cast<const float4*>(bv + v0);
#pragma unroll
      for (int m = 0; m < MROWS; ++m) {
        float l0 = acc[m].x + b4.x, l1 = acc[m].y + b4.y;
        float l2 = acc[m].z + b4.z, l3 = acc[m].w + b4.w;
        int lb = ll[m] - v0;
        if (lb >= 0 && lb < 4) {
          tgt[m] = (lb == 0) ? l0 : (lb == 1) ? l1 : (lb == 2) ? l2 : l3;
        }
        float tm = fmaxf(fmaxf(l0, l1), fmaxf(l2, l3));
        float nm = fmaxf(mx[m], tm);
        sm[m] = sm[m] * expf(mx[m] - nm)
              + expf(l0 - nm) + expf(l1 - nm) + expf(l2 - nm) + expf(l3 - nm);
        mx[m] = nm;
      }
    }
  }

#pragma unroll
  for (int m = 0; m < MROWS; ++m) {
#pragma unroll
    for (int off = 32; off >= 1; off >>= 1) {
      float om = __shfl_xor(mx[m], off, 64);
      float os = __shfl_xor(sm[m], off, 64);
      float nm = fmaxf(mx[m], om);
      sm[m] = sm[m] * expf(mx[m] - nm) + os * expf(om - nm);
      mx[m] = nm;
    }
  }
  int wid = tid >> 6;
  if ((tid & 63) == 0) {
#pragma unroll
    for (int m = 0; m < MROWS; ++m) { wmax[m][wid] = mx[m]; wsum[m][wid] = sm[m]; }
  }
  __syncthreads();

  if (tid < MROWS) {
    float M = wmax[tid][0], S = wsum[tid][0];
#pragma unroll
    for (int w = 1; w < 4; ++w) {
      float om = wmax[tid][w], os = wsum[tid][w];
      float nm = fmaxf(M, om);
      S = S * expf(M - nm) + os * expf(om - nm);
      M = nm;
    }
    float loss = (M + logf(S)) - tgt[tid];
    atomicAdd(accum, loss);
  }
}

__global__ void finish_k(const float* __restrict__ accum, float* __restrict__ out) {
  out[0] = accum[0] * (1.f / (float)NROW);
}

// ---------------- launcher ----------------
extern "C" void kernel_launch(void* const* d_in, const int* in_sizes, int n_in,
                              void* d_out, int out_size, void* d_ws, size_t ws_size,
                              hipStream_t stream) {
  const int*   ids  = (const int*)  d_in[0];
  const int*   tgts = (const int*)  d_in[1];
  const float* emb  = (const float*)d_in[2];
  const float* W1   = (const float*)d_in[3];
  const float* b1   = (const float*)d_in[4];
  const float* W2   = (const float*)d_in[5];
  const float* b2   = (const float*)d_in[6];
  const float* Wv   = (const float*)d_in[7];
  const float* bv   = (const float*)d_in[8];
  float* out = (float*)d_out;

  // ws layout (bytes):
  //   G1   bf16 [T][B][2048]  33,554,432
  //   outs bf16 [T][B][512]    8,388,608
  //   h1g  bf16 [2][B][512]      131,072
  //   h2g  bf16 [2][B][512]      131,072
  //   cnt  int | accum f32                 total ~42.2 MB
  char* ws = (char*)d_ws;
  unsigned short* G1    = (unsigned short*)(ws);
  unsigned short* outsb = (unsigned short*)(ws + 33554432);
  unsigned short* h1g   = (unsigned short*)(ws + 41943040);
  unsigned short* h2g   = (unsigned short*)(ws + 42074112);
  int*            cnt   = (int*)           (ws + 42205184);
  float*          accum = (float*)         (ws + 42205188);

  // zero h-states + cnt + accum (262,152 B = 65,538 floats)
  zero_k<<<(65538 + 255) / 256, 256, 0, stream>>>((float*)h1g, 65538);

  gemm1_k<<<512, 256, 0, stream>>>(ids, emb, W1, b1, G1);

  {
    void* args[] = { (void*)&W1, (void*)&W2, (void*)&b2, (void*)&G1,
                     (void*)&h1g, (void*)&h2g, (void*)&outsb, (void*)&cnt };
    hipError_t e = hipLaunchCooperativeKernel((const void*)recur_k,
                                              dim3(RBLK), dim3(RTH),
                                              args, 0, stream);
    if (e != hipSuccess) {
      // fallback: plain launch (128 blocks on 256 CUs -> co-resident)
      recur_k<<<dim3(RBLK), dim3(RTH), 0, stream>>>(W1, W2, b2, G1, h1g, h2g,
                                                    outsb, cnt);
    }
  }

  ce_k<<<512, 256, 0, stream>>>(outsb, Wv, bv, tgts, accum);
  finish_k<<<1, 1, 0, stream>>>(accum, out);
}